// Round 32
// baseline (94.993 us; speedup 1.0000x reference)
//
#include <hip/hip_runtime.h>
#include <math.h>

#define N_PTS 16384
#define M_TGT 16384
#define TPN 8192
#define DUB2 4.0f
#define ZWORDS 98560   // bmask 32768 + hist16 65536 + phist 256 (contiguous)

__device__ __forceinline__ unsigned int mono_key(float f) {
    unsigned int u = __float_as_uint(f);
    return (u & 0x80000000u) ? ~u : (u | 0x80000000u);
}

// 33 integer offsets with dx^2+dy^2+dz^2 <= 4; 4th component = d2 group.
__device__ const signed char NOFF4[33][4] = {
    {0,0,0,0},
    {1,0,0,1},{-1,0,0,1},{0,1,0,1},{0,-1,0,1},{0,0,1,1},{0,0,-1,1},
    {1,1,0,2},{1,-1,0,2},{-1,1,0,2},{-1,-1,0,2},{1,0,1,2},{1,0,-1,2},{-1,0,1,2},{-1,0,-1,2},
    {0,1,1,2},{0,1,-1,2},{0,-1,1,2},{0,-1,-1,2},
    {1,1,1,3},{1,1,-1,3},{1,-1,1,3},{1,-1,-1,3},{-1,1,1,3},{-1,1,-1,3},{-1,-1,1,3},{-1,-1,-1,3},
    {2,0,0,4},{-2,0,0,4},{0,2,0,4},{0,-2,0,4},{0,0,2,4},{0,0,-2,4}
};

// wave-0 scan-locate over a 256-bin LDS histogram: find bin containing rank r,
// write bin -> *sh_b, remaining rank -> *sh_r. Caller barriers around it.
__device__ __forceinline__ void scan_locate256(const unsigned int* h256,
        unsigned int r, unsigned int* sh_b, unsigned int* sh_r, int tid) {
    const int lane = tid & 63;
    if ((tid >> 6) == 0) {
        uint4 h = ((const uint4*)h256)[lane];
        unsigned int ss = h.x + h.y + h.z + h.w;
        unsigned int inc = ss;
        for (int d = 1; d < 64; d <<= 1) {
            unsigned int t = __shfl_up(inc, d);
            if (lane >= d) inc += t;
        }
        unsigned int exc = inc - ss;
        bool has = (r >= exc && r < exc + ss);
        unsigned long long m = __ballot(has);
        if (m != 0ull && lane == __ffsll(m) - 1) {
            unsigned int rr = r - exc;
            if (rr < h.x)                   { *sh_b = lane*4u;    *sh_r = rr; }
            else if (rr < h.x+h.y)          { *sh_b = lane*4u+1u; *sh_r = rr-h.x; }
            else if (rr < h.x+h.y+h.z)      { *sh_b = lane*4u+2u; *sh_r = rr-h.x-h.y; }
            else                            { *sh_b = lane*4u+3u; *sh_r = rr-h.x-h.y-h.z; }
        }
    }
}

// K0: zero bmask+hist16+phist (one contiguous 394 KB range).
__global__ __launch_bounds__(256) void k_zero(unsigned int* __restrict__ z) {
    int i = blockIdx.x * 256 + threadIdx.x;
    if (i < ZWORDS) z[i] = 0u;
}

// K1: round-11 proven gemm (16 rows/block) + FUSED scatter tail:
// each block atomicOr's its 16 targets into bmask and histograms its own
// 16 register-resident pred values into hist16/phist (fire-and-forget,
// order-independent integer adds -> deterministic). k_scat eliminated.
__global__ __launch_bounds__(256) void k_gemm(const float* __restrict__ fea,
        const float* __restrict__ Wup, const float* __restrict__ Wcls,
        const int* __restrict__ tcoords,
        float* __restrict__ out_pred, float* __restrict__ out_fea,
        unsigned int* __restrict__ bmask, unsigned int* __restrict__ hist16,
        unsigned int* __restrict__ phist) {
    __shared__ float Ws[64 * 64];
    __shared__ float fs[16 * 68];
    const int tid = threadIdx.x;
    const int r0 = blockIdx.x * 16;

    if (tid < 16) {                          // bitmask: 16 targets per block
        int4 c = *(const int4*)&tcoords[(blockIdx.x * 16 + tid) * 4];
        int key = ((c.x * 64 + c.y) * 64 + c.z) * 64 + c.w;
        atomicOr(&bmask[key >> 5], 1u << (key & 31));
    }

    for (int t = tid; t < 1024; t += 256)
        ((float4*)Ws)[t] = ((const float4*)Wup)[t];
    {
        float4 v = ((const float4*)(fea + r0 * 64))[tid];
        int r = tid >> 4, c = (tid & 15) * 4;
        fs[r*68 + c + 0] = v.x; fs[r*68 + c + 1] = v.y;
        fs[r*68 + c + 2] = v.z; fs[r*68 + c + 3] = v.w;
    }
    __syncthreads();

    const int cg = tid & 15;
    const int r  = tid >> 4;
    float a0 = 0.f, a1 = 0.f, a2 = 0.f, a3 = 0.f;
    const float* fr = fs + r * 68;
    #pragma unroll
    for (int k = 0; k < 64; ++k) {
        float f = fr[k];
        float4 w = *(const float4*)&Ws[k * 64 + cg * 4];
        a0 = fmaf(f, w.x, a0); a1 = fmaf(f, w.y, a1);
        a2 = fmaf(f, w.z, a2); a3 = fmaf(f, w.w, a3);
    }
    a0 = fmaxf(a0, 0.f); a1 = fmaxf(a1, 0.f);
    a2 = fmaxf(a2, 0.f); a3 = fmaxf(a3, 0.f);
    const int row = r0 + r;
    *(float4*)&out_fea[row * 64 + cg * 4] = make_float4(a0, a1, a2, a3);

    float4 wc = *(const float4*)&Wcls[cg * 4];
    float s = a0*wc.x + a1*wc.y + a2*wc.z + a3*wc.w;
    for (int off = 1; off < 16; off <<= 1) s += __shfl_xor(s, off, 16);
    if (cg == 0) {
        out_pred[row] = s;
        unsigned int u = mono_key(s);        // fused pred histograms
        atomicAdd(&hist16[u >> 16], 1u);
        atomicAdd(&phist[u >> 24], 1u);
    }
}

// K3: per-block threshold (phist byte0 -> hist16 slice byte1 -> one pred scan
// + list radix, exact fallback) + parallel probe + WRITE-ONLY epilogue.
// 64 rows/block.
__global__ __launch_bounds__(1024) void k_final(const int* __restrict__ coords,
        const unsigned int* __restrict__ bmask, const unsigned int* __restrict__ phist,
        const unsigned int* __restrict__ hist16,
        const float* __restrict__ out_pred, float* __restrict__ out_fea,
        float* __restrict__ out_keep, float* __restrict__ out_kt,
        float* __restrict__ out_loss) {
    __shared__ unsigned int hA[256];
    __shared__ unsigned int list[1024];
    __shared__ unsigned int sh_b, sh_r, sh_cnt;
    __shared__ float kscale[64];
    const int tid = threadIdx.x;
    const int r0 = blockIdx.x * 64;

    // ---- byte 0: load global 256-bin histogram ----
    if (tid < 256) hA[tid] = phist[tid];
    if (tid == 0) sh_cnt = 0u;
    __syncthreads();
    scan_locate256(hA, TPN - 1, &sh_b, &sh_r, tid);
    __syncthreads();
    const unsigned int b0 = sh_b;
    const unsigned int rank1 = sh_r;

    // ---- byte 1: 1 KB slice of hist16 ----
    if (tid < 256) hA[tid] = hist16[b0 * 256 + tid];
    __syncthreads();
    scan_locate256(hA, rank1, &sh_b, &sh_r, tid);
    __syncthreads();
    const unsigned int bin16 = (b0 << 8) | sh_b;
    const unsigned int rank2 = sh_r;

    // ---- collect keys matching bin16 (low 16 bits) in ONE pred scan ----
    for (int i = tid; i < N_PTS / 4; i += 1024) {
        float4 v = ((const float4*)out_pred)[i];
        unsigned int u0 = mono_key(v.x), u1 = mono_key(v.y);
        unsigned int u2 = mono_key(v.z), u3 = mono_key(v.w);
        if ((u0 >> 16) == bin16) { unsigned int p = atomicAdd(&sh_cnt, 1u); if (p < 1024u) list[p] = u0 & 0xFFFFu; }
        if ((u1 >> 16) == bin16) { unsigned int p = atomicAdd(&sh_cnt, 1u); if (p < 1024u) list[p] = u1 & 0xFFFFu; }
        if ((u2 >> 16) == bin16) { unsigned int p = atomicAdd(&sh_cnt, 1u); if (p < 1024u) list[p] = u2 & 0xFFFFu; }
        if ((u3 >> 16) == bin16) { unsigned int p = atomicAdd(&sh_cnt, 1u); if (p < 1024u) list[p] = u3 & 0xFFFFu; }
    }
    __syncthreads();
    const unsigned int cnt = sh_cnt;
    unsigned int b2, b3;

    if (cnt <= 1024u) {                       // list path (order-independent rank)
        if (tid < 256) hA[tid] = 0u;
        __syncthreads();
        if (tid < (int)cnt) atomicAdd(&hA[list[tid] >> 8], 1u);
        __syncthreads();
        scan_locate256(hA, rank2, &sh_b, &sh_r, tid);
        __syncthreads();
        b2 = sh_b;
        unsigned int rank3 = sh_r;
        if (tid < 256) hA[tid] = 0u;
        __syncthreads();
        if (tid < (int)cnt) { unsigned int e = list[tid]; if ((e >> 8) == b2) atomicAdd(&hA[e & 255u], 1u); }
        __syncthreads();
        scan_locate256(hA, rank3, &sh_b, &sh_r, tid);
        __syncthreads();
        b3 = sh_b;
    } else {                                  // exact fallback: filtered pred scans
        if (tid < 256) hA[tid] = 0u;
        __syncthreads();
        for (int i = tid; i < N_PTS / 4; i += 1024) {
            float4 v = ((const float4*)out_pred)[i];
            unsigned int u0 = mono_key(v.x), u1 = mono_key(v.y);
            unsigned int u2 = mono_key(v.z), u3 = mono_key(v.w);
            if ((u0 >> 16) == bin16) atomicAdd(&hA[(u0 >> 8) & 255u], 1u);
            if ((u1 >> 16) == bin16) atomicAdd(&hA[(u1 >> 8) & 255u], 1u);
            if ((u2 >> 16) == bin16) atomicAdd(&hA[(u2 >> 8) & 255u], 1u);
            if ((u3 >> 16) == bin16) atomicAdd(&hA[(u3 >> 8) & 255u], 1u);
        }
        __syncthreads();
        scan_locate256(hA, rank2, &sh_b, &sh_r, tid);
        __syncthreads();
        b2 = sh_b;
        unsigned int rank3 = sh_r;
        unsigned int pfx24 = (bin16 << 8) | b2;
        if (tid < 256) hA[tid] = 0u;
        __syncthreads();
        for (int i = tid; i < N_PTS / 4; i += 1024) {
            float4 v = ((const float4*)out_pred)[i];
            unsigned int u0 = mono_key(v.x), u1 = mono_key(v.y);
            unsigned int u2 = mono_key(v.z), u3 = mono_key(v.w);
            if ((u0 >> 8) == pfx24) atomicAdd(&hA[u0 & 255u], 1u);
            if ((u1 >> 8) == pfx24) atomicAdd(&hA[u1 & 255u], 1u);
            if ((u2 >> 8) == pfx24) atomicAdd(&hA[u2 & 255u], 1u);
            if ((u3 >> 8) == pfx24) atomicAdd(&hA[u3 & 255u], 1u);
        }
        __syncthreads();
        scan_locate256(hA, rank3, &sh_b, &sh_r, tid);
        __syncthreads();
        b3 = sh_b;
    }
    const unsigned int uth = (bin16 << 16) | (b2 << 8) | b3;
    const float thres = (uth & 0x80000000u) ? __uint_as_float(uth ^ 0x80000000u)
                                            : __uint_as_float(~uth);

    // ---- parallel probe: 16 threads/row, 2 offsets each + shfl-min ----
    {
        const int row = tid >> 4;
        const int sub = tid & 15;
        const int i = r0 + row;
        float p = out_pred[i];
        int4 c = *(const int4*)&coords[i * 4];
        const int b = c.x, x = c.y, y = c.z, z = c.w;
        int key0 = ((b * 64 + x) * 64 + y) * 64 + z;
        bool kt = (bmask[key0 >> 5] >> (key0 & 31)) & 1u;
        float dists;
        if (kt) {
            dists = 0.f;
        } else {
            float best = 5.f;                 // sentinel > DUB2: "not found"
            #pragma unroll
            for (int q = 0; q < 2; ++q) {
                int t = 1 + sub + q * 16;     // t in [1,33)
                int ox = x + NOFF4[t][0], oy = y + NOFF4[t][1], oz = z + NOFF4[t][2];
                if (((unsigned)ox | (unsigned)oy | (unsigned)oz) < 64u) {
                    int key = ((b * 64 + ox) * 64 + oy) * 64 + oz;
                    if ((bmask[key >> 5] >> (key & 31)) & 1u)
                        best = fminf(best, (float)NOFF4[t][3]);
                }
            }
            for (int d = 1; d < 16; d <<= 1)
                best = fminf(best, __shfl_xor(best, d, 16));
            dists = best;
        }
        if (sub == 0) {
            bool keep0 = (p <= thres);
            bool pm = (p > DUB2), tm = (dists > DUB2);
            float loss = (pm && tm) ? p : ((!pm && tm) ? DUB2 : dists);
            bool kf = keep0 || kt;
            out_keep[i] = kf ? 1.f : 0.f;
            out_kt[i]  = kt ? 1.f : 0.f;
            out_loss[i] = loss;
            kscale[row] = kf ? 1.f : 0.f;
        }
    }
    __syncthreads();
    {   // write-only epilogue: zero non-kept rows (kept rows already hold fea_up)
        float4* fbase = (float4*)(out_fea + r0 * 64);
        int v = tid;                          // 64 rows x 16 float4 = 1024
        if (kscale[v >> 4] == 0.f)
            fbase[v] = make_float4(0.f, 0.f, 0.f, 0.f);
    }
}

extern "C" void kernel_launch(void* const* d_in, const int* in_sizes, int n_in,
                              void* d_out, int out_size, void* d_ws, size_t ws_size,
                              hipStream_t stream) {
    const float* fea     = (const float*)d_in[0];
    const float* Wup     = (const float*)d_in[1];
    const float* Wcls    = (const float*)d_in[2];
    const int*   coords  = (const int*)d_in[3];
    const int*   tcoords = (const int*)d_in[4];

    float* out      = (float*)d_out;
    float* out_pred = out;
    float* out_fea  = out + N_PTS;
    float* out_keep = out + N_PTS + N_PTS * 64;
    float* out_kt   = out_keep + N_PTS;
    float* out_loss = out_kt + N_PTS;

    char* ws = (char*)d_ws;
    unsigned int* zbase  = (unsigned int*)(ws + 64);       // contiguous zero range
    unsigned int* bmask  = (unsigned int*)(ws + 64);       // 128 KB -> 131136
    unsigned int* hist16 = (unsigned int*)(ws + 131136);   // 256 KB -> 393280
    unsigned int* phist  = (unsigned int*)(ws + 393280);   // 1 KB   -> 394304

    k_zero <<<(ZWORDS + 255) / 256, 256, 0, stream>>>(zbase);
    k_gemm <<<N_PTS / 16, 256, 0, stream>>>(fea, Wup, Wcls, tcoords,
                                            out_pred, out_fea, bmask, hist16, phist);
    k_final<<<N_PTS / 64, 1024, 0, stream>>>(coords, bmask, phist, hist16,
                                             out_pred, out_fea, out_keep, out_kt, out_loss);
}

// Round 33
// 25.684 us; speedup vs baseline: 3.6986x; 3.6986x over previous
//
#include <hip/hip_runtime.h>
#include <math.h>

#define N_PTS 16384
#define M_TGT 16384
#define TPN 8192
#define DUB2 4.0f
#define BMASK_WORDS (4*64*64*64/32)
#define SCAT_NB 16

__device__ __forceinline__ unsigned int mono_key(float f) {
    unsigned int u = __float_as_uint(f);
    return (u & 0x80000000u) ? ~u : (u | 0x80000000u);
}

// 33 integer offsets with dx^2+dy^2+dz^2 <= 4; 4th component = d2 group.
__device__ const signed char NOFF4[33][4] = {
    {0,0,0,0},
    {1,0,0,1},{-1,0,0,1},{0,1,0,1},{0,-1,0,1},{0,0,1,1},{0,0,-1,1},
    {1,1,0,2},{1,-1,0,2},{-1,1,0,2},{-1,-1,0,2},{1,0,1,2},{1,0,-1,2},{-1,0,1,2},{-1,0,-1,2},
    {0,1,1,2},{0,1,-1,2},{0,-1,1,2},{0,-1,-1,2},
    {1,1,1,3},{1,1,-1,3},{1,-1,1,3},{1,-1,-1,3},{-1,1,1,3},{-1,1,-1,3},{-1,-1,1,3},{-1,-1,-1,3},
    {2,0,0,4},{-2,0,0,4},{0,2,0,4},{0,-2,0,4},{0,0,2,4},{0,0,-2,4}
};

// wave-0 scan-locate over a 256-bin LDS histogram: find bin containing rank r,
// write bin -> *sh_b, remaining rank -> *sh_r. Caller barriers around it.
__device__ __forceinline__ void scan_locate256(const unsigned int* h256,
        unsigned int r, unsigned int* sh_b, unsigned int* sh_r, int tid) {
    const int lane = tid & 63;
    if ((tid >> 6) == 0) {
        uint4 h = ((const uint4*)h256)[lane];
        unsigned int ss = h.x + h.y + h.z + h.w;
        unsigned int inc = ss;
        for (int d = 1; d < 64; d <<= 1) {
            unsigned int t = __shfl_up(inc, d);
            if (lane >= d) inc += t;
        }
        unsigned int exc = inc - ss;
        bool has = (r >= exc && r < exc + ss);
        unsigned long long m = __ballot(has);
        if (m != 0ull && lane == __ffsll(m) - 1) {
            unsigned int rr = r - exc;
            if (rr < h.x)                   { *sh_b = lane*4u;    *sh_r = rr; }
            else if (rr < h.x+h.y)          { *sh_b = lane*4u+1u; *sh_r = rr-h.x; }
            else if (rr < h.x+h.y+h.z)      { *sh_b = lane*4u+2u; *sh_r = rr-h.x-h.y; }
            else                            { *sh_b = lane*4u+3u; *sh_r = rr-h.x-h.y-h.z; }
        }
    }
}

// K1: round-11 proven gemm (16 rows/block). Zeroes bmask + hist16 + phist.
__global__ __launch_bounds__(256) void k_gemm(const float* __restrict__ fea,
        const float* __restrict__ Wup, const float* __restrict__ Wcls,
        float* __restrict__ out_pred, float* __restrict__ out_fea,
        unsigned int* __restrict__ bmask, unsigned int* __restrict__ hist16,
        unsigned int* __restrict__ phist) {
    __shared__ float Ws[64 * 64];
    __shared__ float fs[16 * 68];
    const int tid = threadIdx.x;
    const int r0 = blockIdx.x * 16;

    if (tid < 32) bmask[blockIdx.x * 32 + tid] = 0u;            // 1024*32 = 32768
    else if (tid < 96) hist16[blockIdx.x * 64 + tid - 32] = 0u; // 1024*64 = 65536
    else if (tid < 100) phist[blockIdx.x * 4 + tid - 96] = 0u;  // 1024*4  = 4096

    for (int t = tid; t < 1024; t += 256)
        ((float4*)Ws)[t] = ((const float4*)Wup)[t];
    {
        float4 v = ((const float4*)(fea + r0 * 64))[tid];
        int r = tid >> 4, c = (tid & 15) * 4;
        fs[r*68 + c + 0] = v.x; fs[r*68 + c + 1] = v.y;
        fs[r*68 + c + 2] = v.z; fs[r*68 + c + 3] = v.w;
    }
    __syncthreads();

    const int cg = tid & 15;
    const int r  = tid >> 4;
    float a0 = 0.f, a1 = 0.f, a2 = 0.f, a3 = 0.f;
    const float* fr = fs + r * 68;
    #pragma unroll
    for (int k = 0; k < 64; ++k) {
        float f = fr[k];
        float4 w = *(const float4*)&Ws[k * 64 + cg * 4];
        a0 = fmaf(f, w.x, a0); a1 = fmaf(f, w.y, a1);
        a2 = fmaf(f, w.z, a2); a3 = fmaf(f, w.w, a3);
    }
    a0 = fmaxf(a0, 0.f); a1 = fmaxf(a1, 0.f);
    a2 = fmaxf(a2, 0.f); a3 = fmaxf(a3, 0.f);
    const int row = r0 + r;
    *(float4*)&out_fea[row * 64 + cg * 4] = make_float4(a0, a1, a2, a3);

    float4 wc = *(const float4*)&Wcls[cg * 4];
    float s = a0*wc.x + a1*wc.y + a2*wc.z + a3*wc.w;
    for (int off = 1; off < 16; off <<= 1) s += __shfl_xor(s, off, 16);
    if (cg == 0) out_pred[row] = s;
}

// K2: 64 blocks x 256 threads. Bitmask build + per-wave byte-0 hist ->
// LDS-aggregated atomicAdd into phist slot blk>>2 (4 blocks/slot) +
// global hist16 atomicAdd (top 16 bits). LDS pre-aggregation is MANDATORY
// for phist: round-32's per-lane fire-and-forget atomics on the ~10 hot
// byte-0 bins serialized at L2 and cost 70+ us.
__global__ __launch_bounds__(256) void k_scat(const float* __restrict__ pred,
        const int* __restrict__ tc, unsigned int* __restrict__ bmask,
        unsigned int* __restrict__ phist, unsigned int* __restrict__ hist16) {
    __shared__ unsigned int whist[4][256];
    const int tid = threadIdx.x;
    const int blk = blockIdx.x;
    const int id = blk * 256 + tid;

    for (int t = tid; t < 4 * 256; t += 256) ((unsigned int*)whist)[t] = 0u;

    int4 c = *(const int4*)&tc[id * 4];
    int key = ((c.x * 64 + c.y) * 64 + c.z) * 64 + c.w;
    atomicOr(&bmask[key >> 5], 1u << (key & 31));

    __syncthreads();
    unsigned int u = mono_key(pred[id]);
    atomicAdd(&whist[tid >> 6][u >> 24], 1u);
    atomicAdd(&hist16[u >> 16], 1u);
    __syncthreads();
    {
        unsigned int s = whist[0][tid] + whist[1][tid] + whist[2][tid] + whist[3][tid];
        if (s) atomicAdd(&phist[(blk >> 2) * 256 + tid], s);
    }
}

// K3: per-block threshold (phist byte0 -> hist16 slice byte1 -> one pred scan
// + list radix, exact fallback) + parallel probe + WRITE-ONLY epilogue.
// 64 rows/block.
__global__ __launch_bounds__(1024) void k_final(const int* __restrict__ coords,
        const unsigned int* __restrict__ bmask, const unsigned int* __restrict__ phist,
        const unsigned int* __restrict__ hist16,
        const float* __restrict__ out_pred, float* __restrict__ out_fea,
        float* __restrict__ out_keep, float* __restrict__ out_kt,
        float* __restrict__ out_loss) {
    __shared__ unsigned int hA[256];
    __shared__ unsigned int list[1024];
    __shared__ unsigned int sh_b, sh_r, sh_cnt;
    __shared__ float kscale[64];
    const int tid = threadIdx.x;
    const int r0 = blockIdx.x * 64;

    // ---- byte 0: sum phist partials ----
    if (tid < 256) {
        unsigned int s = 0u;
        #pragma unroll
        for (int b = 0; b < SCAT_NB; ++b) s += phist[b * 256 + tid];
        hA[tid] = s;
    }
    if (tid == 0) sh_cnt = 0u;
    __syncthreads();
    scan_locate256(hA, TPN - 1, &sh_b, &sh_r, tid);
    __syncthreads();
    const unsigned int b0 = sh_b;
    const unsigned int rank1 = sh_r;

    // ---- byte 1: 1 KB slice of hist16 ----
    if (tid < 256) hA[tid] = hist16[b0 * 256 + tid];
    __syncthreads();
    scan_locate256(hA, rank1, &sh_b, &sh_r, tid);
    __syncthreads();
    const unsigned int bin16 = (b0 << 8) | sh_b;
    const unsigned int rank2 = sh_r;

    // ---- collect keys matching bin16 (low 16 bits) in ONE pred scan ----
    for (int i = tid; i < N_PTS / 4; i += 1024) {
        float4 v = ((const float4*)out_pred)[i];
        unsigned int u0 = mono_key(v.x), u1 = mono_key(v.y);
        unsigned int u2 = mono_key(v.z), u3 = mono_key(v.w);
        if ((u0 >> 16) == bin16) { unsigned int p = atomicAdd(&sh_cnt, 1u); if (p < 1024u) list[p] = u0 & 0xFFFFu; }
        if ((u1 >> 16) == bin16) { unsigned int p = atomicAdd(&sh_cnt, 1u); if (p < 1024u) list[p] = u1 & 0xFFFFu; }
        if ((u2 >> 16) == bin16) { unsigned int p = atomicAdd(&sh_cnt, 1u); if (p < 1024u) list[p] = u2 & 0xFFFFu; }
        if ((u3 >> 16) == bin16) { unsigned int p = atomicAdd(&sh_cnt, 1u); if (p < 1024u) list[p] = u3 & 0xFFFFu; }
    }
    __syncthreads();
    const unsigned int cnt = sh_cnt;
    unsigned int b2, b3;

    if (cnt <= 1024u) {                       // list path (order-independent rank)
        if (tid < 256) hA[tid] = 0u;
        __syncthreads();
        if (tid < (int)cnt) atomicAdd(&hA[list[tid] >> 8], 1u);
        __syncthreads();
        scan_locate256(hA, rank2, &sh_b, &sh_r, tid);
        __syncthreads();
        b2 = sh_b;
        unsigned int rank3 = sh_r;
        if (tid < 256) hA[tid] = 0u;
        __syncthreads();
        if (tid < (int)cnt) { unsigned int e = list[tid]; if ((e >> 8) == b2) atomicAdd(&hA[e & 255u], 1u); }
        __syncthreads();
        scan_locate256(hA, rank3, &sh_b, &sh_r, tid);
        __syncthreads();
        b3 = sh_b;
    } else {                                  // exact fallback: filtered pred scans
        if (tid < 256) hA[tid] = 0u;
        __syncthreads();
        for (int i = tid; i < N_PTS / 4; i += 1024) {
            float4 v = ((const float4*)out_pred)[i];
            unsigned int u0 = mono_key(v.x), u1 = mono_key(v.y);
            unsigned int u2 = mono_key(v.z), u3 = mono_key(v.w);
            if ((u0 >> 16) == bin16) atomicAdd(&hA[(u0 >> 8) & 255u], 1u);
            if ((u1 >> 16) == bin16) atomicAdd(&hA[(u1 >> 8) & 255u], 1u);
            if ((u2 >> 16) == bin16) atomicAdd(&hA[(u2 >> 8) & 255u], 1u);
            if ((u3 >> 16) == bin16) atomicAdd(&hA[(u3 >> 8) & 255u], 1u);
        }
        __syncthreads();
        scan_locate256(hA, rank2, &sh_b, &sh_r, tid);
        __syncthreads();
        b2 = sh_b;
        unsigned int rank3 = sh_r;
        unsigned int pfx24 = (bin16 << 8) | b2;
        if (tid < 256) hA[tid] = 0u;
        __syncthreads();
        for (int i = tid; i < N_PTS / 4; i += 1024) {
            float4 v = ((const float4*)out_pred)[i];
            unsigned int u0 = mono_key(v.x), u1 = mono_key(v.y);
            unsigned int u2 = mono_key(v.z), u3 = mono_key(v.w);
            if ((u0 >> 8) == pfx24) atomicAdd(&hA[u0 & 255u], 1u);
            if ((u1 >> 8) == pfx24) atomicAdd(&hA[u1 & 255u], 1u);
            if ((u2 >> 8) == pfx24) atomicAdd(&hA[u2 & 255u], 1u);
            if ((u3 >> 8) == pfx24) atomicAdd(&hA[u3 & 255u], 1u);
        }
        __syncthreads();
        scan_locate256(hA, rank3, &sh_b, &sh_r, tid);
        __syncthreads();
        b3 = sh_b;
    }
    const unsigned int uth = (bin16 << 16) | (b2 << 8) | b3;
    const float thres = (uth & 0x80000000u) ? __uint_as_float(uth ^ 0x80000000u)
                                            : __uint_as_float(~uth);

    // ---- parallel probe: 16 threads/row, 2 offsets each + shfl-min ----
    {
        const int row = tid >> 4;
        const int sub = tid & 15;
        const int i = r0 + row;
        float p = out_pred[i];
        int4 c = *(const int4*)&coords[i * 4];
        const int b = c.x, x = c.y, y = c.z, z = c.w;
        int key0 = ((b * 64 + x) * 64 + y) * 64 + z;
        bool kt = (bmask[key0 >> 5] >> (key0 & 31)) & 1u;
        float dists;
        if (kt) {
            dists = 0.f;
        } else {
            float best = 5.f;                 // sentinel > DUB2: "not found"
            #pragma unroll
            for (int q = 0; q < 2; ++q) {
                int t = 1 + sub + q * 16;     // t in [1,33)
                int ox = x + NOFF4[t][0], oy = y + NOFF4[t][1], oz = z + NOFF4[t][2];
                if (((unsigned)ox | (unsigned)oy | (unsigned)oz) < 64u) {
                    int key = ((b * 64 + ox) * 64 + oy) * 64 + oz;
                    if ((bmask[key >> 5] >> (key & 31)) & 1u)
                        best = fminf(best, (float)NOFF4[t][3]);
                }
            }
            for (int d = 1; d < 16; d <<= 1)
                best = fminf(best, __shfl_xor(best, d, 16));
            dists = best;
        }
        if (sub == 0) {
            bool keep0 = (p <= thres);
            bool pm = (p > DUB2), tm = (dists > DUB2);
            float loss = (pm && tm) ? p : ((!pm && tm) ? DUB2 : dists);
            bool kf = keep0 || kt;
            out_keep[i] = kf ? 1.f : 0.f;
            out_kt[i]  = kt ? 1.f : 0.f;
            out_loss[i] = loss;
            kscale[row] = kf ? 1.f : 0.f;
        }
    }
    __syncthreads();
    {   // write-only epilogue: zero non-kept rows (kept rows already hold fea_up)
        float4* fbase = (float4*)(out_fea + r0 * 64);
        int v = tid;                          // 64 rows x 16 float4 = 1024
        if (kscale[v >> 4] == 0.f)
            fbase[v] = make_float4(0.f, 0.f, 0.f, 0.f);
    }
}

extern "C" void kernel_launch(void* const* d_in, const int* in_sizes, int n_in,
                              void* d_out, int out_size, void* d_ws, size_t ws_size,
                              hipStream_t stream) {
    const float* fea     = (const float*)d_in[0];
    const float* Wup     = (const float*)d_in[1];
    const float* Wcls    = (const float*)d_in[2];
    const int*   coords  = (const int*)d_in[3];
    const int*   tcoords = (const int*)d_in[4];

    float* out      = (float*)d_out;
    float* out_pred = out;
    float* out_fea  = out + N_PTS;
    float* out_keep = out + N_PTS + N_PTS * 64;
    float* out_kt   = out_keep + N_PTS;
    float* out_loss = out_kt + N_PTS;

    char* ws = (char*)d_ws;
    unsigned int* bmask  = (unsigned int*)(ws + 64);       // 128 KB -> 131136
    unsigned int* hist16 = (unsigned int*)(ws + 131136);   // 256 KB -> 393280
    unsigned int* phist  = (unsigned int*)(ws + 393280);   // 16 KB  (16 x 256 u32)

    k_gemm <<<N_PTS / 16, 256, 0, stream>>>(fea, Wup, Wcls, out_pred, out_fea,
                                            bmask, hist16, phist);
    k_scat <<<64, 256, 0, stream>>>(out_pred, tcoords, bmask, phist, hist16);
    k_final<<<N_PTS / 64, 1024, 0, stream>>>(coords, bmask, phist, hist16,
                                             out_pred, out_fea, out_keep, out_kt, out_loss);
}